// Round 12
// baseline (178.545 us; speedup 1.0000x reference)
//
#include <hip/hip_runtime.h>
#include <math.h>

// PixelEachSubstitutor — round 12: within-capture A/B.
//   pixel_main_v7:  1 pixel/wave (64 lanes), champion       pixels [0,7200)
//   pixel_main_v2p: 2 pixels/wave (32-lane groups, halved   pixels [7200,14400)
//                   sync count, no P5 exchange, LDS 22528)
// r11 verdict: vectorized front LOST (bank conflicts 3.4x). Scalar front,
// shuffle tail frozen. History: only occupancy/TLP levers have won; this
// tests sync-frequency vs residency (7 vs 8 blocks/CU).

__device__ __forceinline__ float gsum32(float v) {
#pragma unroll
  for (int m = 16; m > 0; m >>= 1) v += __shfl_xor(v, m, 32);
  return v;
}

__device__ __forceinline__ void wsync() {
  asm volatile("s_waitcnt lgkmcnt(0)" ::: "memory");
}

// ---------------------------------------------------------------------------
// Precompute kernel (2 independent blocks, 256 threads each) — r7 verbatim.
// ---------------------------------------------------------------------------
__global__ __launch_bounds__(256) void precompute_kernel(
    const float* __restrict__ Vf,          // (10,32)
    const float* __restrict__ enc_in,      // (33,11)
    const float* __restrict__ enc_outw,    // (11,11)
    const float* __restrict__ ffV_w,       // (32,81)
    const float* __restrict__ dec_sa_in,   // (96,32)
    const float* __restrict__ dec_sa_out,  // (32,32)
    const float* __restrict__ dec_ln1,     // (32)
    const float* __restrict__ dec_ca_in,   // (96,32)
    float* __restrict__ M_enc, float* __restrict__ WVO,
    float* __restrict__ G_k, float* __restrict__ G_v,
    float* __restrict__ y1, float* __restrict__ qca)
{
  const int tid = threadIdx.x;

  if (blockIdx.x == 0) {
    const float rs11 = 0.3015113445777636f;  // 1/sqrt(11)
    for (int idx = tid; idx < 121; idx += 256) {
      int c = idx / 11, cp = idx - c * 11;
      float sm = 0.f, sv = 0.f;
      for (int i = 0; i < 11; ++i) {
        sm += enc_in[i * 11 + c] * enc_in[(11 + i) * 11 + cp];
        sv += enc_outw[c * 11 + i] * enc_in[(22 + i) * 11 + cp];
      }
      M_enc[idx] = sm * rs11;
      WVO[idx] = sv;
    }

    __shared__ float Fsh[320];
    for (int idx = tid; idx < 288; idx += 256) {
      int t = idx >> 5, j = idx & 31;
      Fsh[idx] = ffV_w[j * 81 + t];
    }
    if (tid < 32) {
      float s = 0.f;
      for (int t = 9; t < 81; ++t) s += ffV_w[tid * 81 + t];
      Fsh[288 + tid] = s;
    }
    __syncthreads();

    for (int idx = tid; idx < 640; idx += 256) {
      int which = idx >= 320;
      int r = idx - 320 * which;
      int t = r >> 5, h = r & 31;
      const float* w = dec_ca_in + ((which ? 64 : 32) + h) * 32;
      float s = 0.f;
      for (int j = 0; j < 32; ++j) s += Fsh[t * 32 + j] * w[j];
      (which ? G_v : G_k)[r] = s;
    }
  } else {
    __shared__ float qsa[320], ksa[320], vsa[320], osa[320], zb[320];
    __shared__ float mu[16], rstd[16];

    for (int idx = tid; idx < 960; idx += 256) {
      int m = idx / 320, r = idx - m * 320;
      int t = r >> 5, h = r & 31;
      const float* w = dec_sa_in + (m * 32 + h) * 32;
      const float* yr = Vf + t * 32;
      float s = 0.f;
#pragma unroll
      for (int j = 0; j < 32; ++j) s += yr[j] * w[j];
      (m == 0 ? qsa : m == 1 ? ksa : vsa)[r] = s;
    }
    __syncthreads();

    for (int idx = tid; idx < 320; idx += 256) {  // nhead=32, hd=1
      int h = idx & 31;
      float q = qsa[idx];
      float sc[10];
      float mx = -1e30f;
#pragma unroll
      for (int s = 0; s < 10; ++s) { sc[s] = q * ksa[s * 32 + h]; mx = fmaxf(mx, sc[s]); }
      float den = 0.f, acc = 0.f;
#pragma unroll
      for (int s = 0; s < 10; ++s) {
        float e = __expf(sc[s] - mx);
        den += e;
        acc += e * vsa[s * 32 + h];
      }
      osa[idx] = acc / den;
    }
    __syncthreads();

    for (int idx = tid; idx < 320; idx += 256) {
      int t = idx >> 5, c = idx & 31;
      float s = 0.f;
#pragma unroll
      for (int h = 0; h < 32; ++h) s += osa[t * 32 + h] * dec_sa_out[c * 32 + h];
      zb[idx] = Vf[idx] + s;
    }
    __syncthreads();

    if (tid < 10) {
      float s1 = 0.f, s2 = 0.f;
      for (int c = 0; c < 32; ++c) { float z = zb[tid * 32 + c]; s1 += z; s2 += z * z; }
      float m = s1 * (1.f / 32.f);
      mu[tid] = m;
      rstd[tid] = 1.f / sqrtf(s2 * (1.f / 32.f) - m * m + 1e-5f);
    }
    __syncthreads();

    for (int idx = tid; idx < 320; idx += 256) {
      int t = idx >> 5, c = idx & 31;
      float v = (zb[idx] - mu[t]) * rstd[t] * dec_ln1[c];
      y1[idx] = v;
      zb[idx] = v;
    }
    __syncthreads();

    for (int idx = tid; idx < 320; idx += 256) {  // qca = y1 @ Wq_ca.T
      int t = idx >> 5, h = idx & 31;
      const float* w = dec_ca_in + h * 32;
      float s = 0.f;
#pragma unroll
      for (int j = 0; j < 32; ++j) s += zb[t * 32 + j] * w[j];
      qca[idx] = s;
    }
  }
}

#define SLICE 704

// ===========================================================================
// VARIANT v7: 1 pixel/wave (r7 verbatim), pixels [0, 7200)
// ===========================================================================
__global__ __launch_bounds__(256) void pixel_main_v7(
    const float* __restrict__ x,
    const float* __restrict__ M_enc, const float* __restrict__ WVO,
    const float* __restrict__ enc_lin1, const float* __restrict__ enc_lin2,
    const float* __restrict__ enc_ln1, const float* __restrict__ enc_ln2,
    const float* __restrict__ G_k, const float* __restrict__ G_v,
    const float* __restrict__ y1g, const float* __restrict__ qcag,
    const float* __restrict__ dec_ca_out,
    const float* __restrict__ dec_lin1, const float* __restrict__ dec_lin2,
    const float* __restrict__ dec_ln2v, const float* __restrict__ dec_ln3v,
    const float* __restrict__ W_d0, const float* __restrict__ W_d1,
    float* __restrict__ out)
{
  __shared__ __align__(16) float sh[4 * SLICE];
  const int wave = threadIdx.x >> 6;
  const int lane = threadIdx.x & 63;
  float* ls = sh + wave * SLICE;
  const int F9 = 0, G = 112, VO = 224, SC = 336, ZR = 432, FET = 544;
  const int OC = 0, ZB = 320;

  const int p = blockIdx.x * 4 + wave;
  const int n = p / 900;
  const int rem = p - n * 900;
  const int pi = rem / 30, pj = rem - (rem / 30) * 30;

  for (int idx = lane; idx < 99; idx += 64) {
    int t = idx / 11, c = idx - t * 11;
    float val = 1.0f;
    if (c < 10) {
      int di = t / 3, dj = t - (t / 3) * 3;
      int ii = pi + di - 1, jj = pj + dj - 1;
      val = (ii >= 0 && ii < 30 && jj >= 0 && jj < 30)
                ? x[((n * 10 + c) * 30 + ii) * 30 + jj] : 0.0f;
    }
    ls[F9 + idx] = val;
  }
  wsync();

  for (int idx = lane; idx < 99; idx += 64) {
    int s = idx / 11, c = idx - (idx / 11) * 11;
    const float* Mr = M_enc + c * 11;
    const float* Wr = WVO + c * 11;
    float ag = 0.f, av = 0.f;
#pragma unroll
    for (int cp = 0; cp < 11; ++cp) {
      float fv = ls[F9 + s * 11 + cp];
      ag += Mr[cp] * fv;
      av += Wr[cp] * fv;
    }
    ls[G + idx] = ag;
    ls[VO + idx] = av;
  }
  wsync();

  for (int idx = lane; idx < 81; idx += 64) {
    int t = idx / 9, s = idx - (idx / 9) * 9;
    float a = 0.f;
#pragma unroll
    for (int c = 0; c < 11; ++c) a += ls[F9 + t * 11 + c] * ls[G + s * 11 + c];
    ls[SC + idx] = a;
  }
  wsync();

  if (lane < 9) {
    float e[9];
    float mx = 0.0f;
#pragma unroll
    for (int s = 0; s < 9; ++s) { e[s] = ls[SC + lane * 9 + s]; mx = fmaxf(mx, e[s]); }
    float den = 72.0f * __expf(-mx);
#pragma unroll
    for (int s = 0; s < 9; ++s) {
      e[s] = __expf(e[s] - mx);
      den += e[s];
      ls[SC + lane * 9 + s] = e[s];
    }
    ls[SC + 81 + lane] = 1.0f / den;
  }
  wsync();

  for (int idx = lane; idx < 110; idx += 64) {
    int t = idx / 11, c = idx - (idx / 11) * 11;
    float a = 0.f;
    if (t < 9) {
#pragma unroll
      for (int s = 0; s < 9; ++s) a += ls[SC + t * 9 + s] * ls[VO + s * 11 + c];
      a = a * ls[SC + 81 + t] + ls[F9 + idx];
    } else {
#pragma unroll
      for (int s = 0; s < 9; ++s) a += ls[VO + s * 11 + c];
      a *= (1.0f / 81.0f);
    }
    ls[ZR + idx] = a;
  }
  wsync();

  if (lane < 10) {
    float row[11];
#pragma unroll
    for (int c = 0; c < 11; ++c) row[c] = ls[ZR + lane * 11 + c];
    float s1 = 0.f, s2 = 0.f;
#pragma unroll
    for (int c = 0; c < 11; ++c) { s1 += row[c]; s2 += row[c] * row[c]; }
    float mu = s1 * (1.0f / 11.0f);
    float rs = 1.0f / sqrtf(s2 * (1.0f / 11.0f) - mu * mu + 1e-5f);
    float h = 0.f;
#pragma unroll
    for (int c = 0; c < 11; ++c) {
      row[c] = (row[c] - mu) * rs * enc_ln1[c];
      h += row[c] * enc_lin1[c];
    }
    h = fmaxf(h, 0.f);
    float t1 = 0.f, t2 = 0.f;
#pragma unroll
    for (int c = 0; c < 11; ++c) {
      row[c] += h * enc_lin2[c];
      t1 += row[c]; t2 += row[c] * row[c];
    }
    float mu2 = t1 * (1.0f / 11.0f);
    float rs2 = 1.0f / sqrtf(t2 * (1.0f / 11.0f) - mu2 * mu2 + 1e-5f);
#pragma unroll
    for (int c = 0; c < 11; ++c)
      ls[FET + c * 12 + lane] = (row[c] - mu2) * rs2 * enc_ln2[c];
  }
  wsync();

  const int hh = lane & 31, grp = lane >> 5;
  float kv[11];
  {
    const float* Gb = grp ? G_v : G_k;
    float gr[10];
#pragma unroll
    for (int t = 0; t < 10; ++t) gr[t] = Gb[t * 32 + hh];
#pragma unroll
    for (int cc = 0; cc < 11; ++cc) {
      const float4* fr = (const float4*)(ls + FET + cc * 12);
      float4 a = fr[0], b4 = fr[1], c4 = fr[2];
      float fe[10] = {a.x, a.y, a.z, a.w, b4.x, b4.y, b4.z, b4.w, c4.x, c4.y};
      float s = 0.f;
#pragma unroll
      for (int t = 0; t < 10; ++t) s += fe[t] * gr[t];
      kv[cc] = s;
    }
  }
  float kk[11], vv[11];
#pragma unroll
  for (int cc = 0; cc < 11; ++cc) {
    float o = __shfl_xor(kv[cc], 32);
    kk[cc] = grp ? o : kv[cc];
    vv[cc] = grp ? kv[cc] : o;
  }

#pragma unroll
  for (int i = 0; i < 5; ++i) {
    int t = grp * 5 + i;
    float q = qcag[t * 32 + hh];
    float sc[11];
    float mx = q * kk[0];
    sc[0] = mx;
#pragma unroll
    for (int s = 1; s < 11; ++s) { sc[s] = q * kk[s]; mx = fmaxf(mx, sc[s]); }
    float den = 0.f, acc = 0.f;
#pragma unroll
    for (int s = 0; s < 11; ++s) {
      float e = __expf(sc[s] - mx);
      den += e;
      acc += e * vv[s];
    }
    ls[OC + t * 32 + hh] = acc / den;
  }
  wsync();

  for (int k = 0; k < 5; ++k) {
    int t = 2 * k + grp;
    int c = hh;
    float zacc = 0.f;
    const float4* wrow = (const float4*)(dec_ca_out + c * 32);
    const float4* orow = (const float4*)(ls + OC + t * 32);
#pragma unroll
    for (int h4 = 0; h4 < 8; ++h4) {
      float4 o4 = orow[h4];
      float4 w4 = wrow[h4];
      zacc += o4.x * w4.x + o4.y * w4.y + o4.z * w4.z + o4.w * w4.w;
    }
    float z = y1g[t * 32 + c] + zacc;
    {
      float s1 = gsum32(z), s2 = gsum32(z * z);
      float mu = s1 * (1.0f / 32.0f);
      z = (z - mu) * (1.0f / sqrtf(s2 * (1.0f / 32.0f) - mu * mu + 1e-5f)) * dec_ln2v[c];
    }
    {
      float d1 = gsum32(z * dec_lin1[c]);
      z += fmaxf(d1, 0.f) * dec_lin2[c];
    }
    {
      float s1 = gsum32(z), s2 = gsum32(z * z);
      float mu = s1 * (1.0f / 32.0f);
      z = (z - mu) * (1.0f / sqrtf(s2 * (1.0f / 32.0f) - mu * mu + 1e-5f)) * dec_ln3v[c];
    }
    ls[ZB + t * 32 + c] = z;
  }
  wsync();

  for (int idx = lane; idx < 80; idx += 64) {
    int t = idx >> 3, m = idx & 7;
    const float4* arow = (const float4*)(W_d0 + m * 32);
    const float4* zrow4 = (const float4*)(ls + ZB + t * 32);
    float d = 0.f;
#pragma unroll
    for (int q4 = 0; q4 < 8; ++q4) {
      float4 a4 = arow[q4];
      float4 z4 = zrow4[q4];
      d += a4.x * z4.x + a4.y * z4.y + a4.z * z4.z + a4.w * z4.w;
    }
    ls[OC + idx] = fmaxf(d, 0.f);
  }
  wsync();

  if (lane < 10) {
    float r = 0.f;
#pragma unroll
    for (int m = 0; m < 8; ++m) r += ls[OC + lane * 8 + m] * W_d1[m];
    out[((n * 10 + lane) * 30 + pi) * 30 + pj] = r;
  }
}

// ===========================================================================
// VARIANT v2p: 2 pixels/wave, 32-lane groups, pixels [7200, 14400)
// Per-pixel wave-instruction counts match v7; syncs per pixel halved;
// P5 exchange removed (lane holds both K and V rows); LDS 8 slices.
// ===========================================================================
__global__ __launch_bounds__(256) void pixel_main_v2p(
    const float* __restrict__ x,
    const float* __restrict__ M_enc, const float* __restrict__ WVO,
    const float* __restrict__ enc_lin1, const float* __restrict__ enc_lin2,
    const float* __restrict__ enc_ln1, const float* __restrict__ enc_ln2,
    const float* __restrict__ G_k, const float* __restrict__ G_v,
    const float* __restrict__ y1g, const float* __restrict__ qcag,
    const float* __restrict__ dec_ca_out,
    const float* __restrict__ dec_lin1, const float* __restrict__ dec_lin2,
    const float* __restrict__ dec_ln2v, const float* __restrict__ dec_ln3v,
    const float* __restrict__ W_d0, const float* __restrict__ W_d1,
    float* __restrict__ out)
{
  __shared__ __align__(16) float sh[8 * SLICE];
  const int wave = threadIdx.x >> 6;
  const int lane = threadIdx.x & 63;
  const int sub = lane >> 5;       // which pixel of this wave's pair
  const int l32 = lane & 31;
  float* ls = sh + (wave * 2 + sub) * SLICE;
  const int F9 = 0, G = 112, VO = 224, SC = 336, ZR = 432, FET = 544;
  const int OC = 0, ZB = 320;

  const int p = 7200 + blockIdx.x * 8 + wave * 2 + sub;
  const int n = p / 900;
  const int rem = p - n * 900;
  const int pi = rem / 30, pj = rem - (rem / 30) * 30;

  // P1
  for (int idx = l32; idx < 99; idx += 32) {
    int t = idx / 11, c = idx - t * 11;
    float val = 1.0f;
    if (c < 10) {
      int di = t / 3, dj = t - (t / 3) * 3;
      int ii = pi + di - 1, jj = pj + dj - 1;
      val = (ii >= 0 && ii < 30 && jj >= 0 && jj < 30)
                ? x[((n * 10 + c) * 30 + ii) * 30 + jj] : 0.0f;
    }
    ls[F9 + idx] = val;
  }
  wsync();

  // P2
  for (int idx = l32; idx < 99; idx += 32) {
    int s = idx / 11, c = idx - (idx / 11) * 11;
    const float* Mr = M_enc + c * 11;
    const float* Wr = WVO + c * 11;
    float ag = 0.f, av = 0.f;
#pragma unroll
    for (int cp = 0; cp < 11; ++cp) {
      float fv = ls[F9 + s * 11 + cp];
      ag += Mr[cp] * fv;
      av += Wr[cp] * fv;
    }
    ls[G + idx] = ag;
    ls[VO + idx] = av;
  }
  wsync();

  // P2b
  for (int idx = l32; idx < 81; idx += 32) {
    int t = idx / 9, s = idx - (idx / 9) * 9;
    float a = 0.f;
#pragma unroll
    for (int c = 0; c < 11; ++c) a += ls[F9 + t * 11 + c] * ls[G + s * 11 + c];
    ls[SC + idx] = a;
  }
  wsync();

  // P3s
  if (l32 < 9) {
    float e[9];
    float mx = 0.0f;
#pragma unroll
    for (int s = 0; s < 9; ++s) { e[s] = ls[SC + l32 * 9 + s]; mx = fmaxf(mx, e[s]); }
    float den = 72.0f * __expf(-mx);
#pragma unroll
    for (int s = 0; s < 9; ++s) {
      e[s] = __expf(e[s] - mx);
      den += e[s];
      ls[SC + l32 * 9 + s] = e[s];
    }
    ls[SC + 81 + l32] = 1.0f / den;
  }
  wsync();

  // P3d
  for (int idx = l32; idx < 110; idx += 32) {
    int t = idx / 11, c = idx - (idx / 11) * 11;
    float a = 0.f;
    if (t < 9) {
#pragma unroll
      for (int s = 0; s < 9; ++s) a += ls[SC + t * 9 + s] * ls[VO + s * 11 + c];
      a = a * ls[SC + 81 + t] + ls[F9 + idx];
    } else {
#pragma unroll
      for (int s = 0; s < 9; ++s) a += ls[VO + s * 11 + c];
      a *= (1.0f / 81.0f);
    }
    ls[ZR + idx] = a;
  }
  wsync();

  // P4s
  if (l32 < 10) {
    float row[11];
#pragma unroll
    for (int c = 0; c < 11; ++c) row[c] = ls[ZR + l32 * 11 + c];
    float s1 = 0.f, s2 = 0.f;
#pragma unroll
    for (int c = 0; c < 11; ++c) { s1 += row[c]; s2 += row[c] * row[c]; }
    float mu = s1 * (1.0f / 11.0f);
    float rs = 1.0f / sqrtf(s2 * (1.0f / 11.0f) - mu * mu + 1e-5f);
    float h = 0.f;
#pragma unroll
    for (int c = 0; c < 11; ++c) {
      row[c] = (row[c] - mu) * rs * enc_ln1[c];
      h += row[c] * enc_lin1[c];
    }
    h = fmaxf(h, 0.f);
    float t1 = 0.f, t2 = 0.f;
#pragma unroll
    for (int c = 0; c < 11; ++c) {
      row[c] += h * enc_lin2[c];
      t1 += row[c]; t2 += row[c] * row[c];
    }
    float mu2 = t1 * (1.0f / 11.0f);
    float rs2 = 1.0f / sqrtf(t2 * (1.0f / 11.0f) - mu2 * mu2 + 1e-5f);
#pragma unroll
    for (int c = 0; c < 11; ++c)
      ls[FET + c * 11 + 0 * 12 + (c * 12 - c * 11) + l32] = 0.f;  // placeholder avoided below
  }
  // NOTE: placeholder above is dead (overwritten); real write follows to keep
  // stride-12 layout identical to v7:
  if (l32 < 10) {
    // recompute is avoided: the block above already wrote nothing live; do the
    // real FET store here from a second pass over ZR (cheap, 10 lanes).
  }
  // --- To keep things simple and identical to v7 semantics, P4s is done in
  // one pass below (replaces the two stubs above).
  wsync();

  if (l32 < 10) {
    float row[11];
#pragma unroll
    for (int c = 0; c < 11; ++c) row[c] = ls[ZR + l32 * 11 + c];
    float s1 = 0.f, s2 = 0.f;
#pragma unroll
    for (int c = 0; c < 11; ++c) { s1 += row[c]; s2 += row[c] * row[c]; }
    float mu = s1 * (1.0f / 11.0f);
    float rs = 1.0f / sqrtf(s2 * (1.0f / 11.0f) - mu * mu + 1e-5f);
    float h = 0.f;
#pragma unroll
    for (int c = 0; c < 11; ++c) {
      row[c] = (row[c] - mu) * rs * enc_ln1[c];
      h += row[c] * enc_lin1[c];
    }
    h = fmaxf(h, 0.f);
    float t1 = 0.f, t2 = 0.f;
#pragma unroll
    for (int c = 0; c < 11; ++c) {
      row[c] += h * enc_lin2[c];
      t1 += row[c]; t2 += row[c] * row[c];
    }
    float mu2 = t1 * (1.0f / 11.0f);
    float rs2 = 1.0f / sqrtf(t2 * (1.0f / 11.0f) - mu2 * mu2 + 1e-5f);
#pragma unroll
    for (int c = 0; c < 11; ++c)
      ls[FET + c * 12 + l32] = (row[c] - mu2) * rs2 * enc_ln2[c];
  }
  wsync();

  // P5: lane l32 computes BOTH K-row and V-row for head l32 (no exchange)
  float kk[11], vv[11];
  {
    float gk[10], gv[10];
#pragma unroll
    for (int t = 0; t < 10; ++t) {
      gk[t] = G_k[t * 32 + l32];
      gv[t] = G_v[t * 32 + l32];
    }
#pragma unroll
    for (int cc = 0; cc < 11; ++cc) {
      const float4* fr = (const float4*)(ls + FET + cc * 12);
      float4 a = fr[0], b4 = fr[1], c4 = fr[2];
      float fe[10] = {a.x, a.y, a.z, a.w, b4.x, b4.y, b4.z, b4.w, c4.x, c4.y};
      float sk = 0.f, sv = 0.f;
#pragma unroll
      for (int t = 0; t < 10; ++t) { sk += fe[t] * gk[t]; sv += fe[t] * gv[t]; }
      kk[cc] = sk;
      vv[cc] = sv;
    }
  }

  // P6: all 10 q-rows for this pixel (both sub-groups lockstep)
#pragma unroll
  for (int t = 0; t < 10; ++t) {
    float q = qcag[t * 32 + l32];
    float sc[11];
    float mx = q * kk[0];
    sc[0] = mx;
#pragma unroll
    for (int s = 1; s < 11; ++s) { sc[s] = q * kk[s]; mx = fmaxf(mx, sc[s]); }
    float den = 0.f, acc = 0.f;
#pragma unroll
    for (int s = 0; s < 11; ++s) {
      float e = __expf(sc[s] - mx);
      den += e;
      acc += e * vv[s];
    }
    ls[OC + t * 32 + l32] = acc / den;
  }
  wsync();

  // P7a: all 10 rows, c = l32; gsum32 is 32-lane-group local
  for (int t = 0; t < 10; ++t) {
    int c = l32;
    float zacc = 0.f;
    const float4* wrow = (const float4*)(dec_ca_out + c * 32);
    const float4* orow = (const float4*)(ls + OC + t * 32);
#pragma unroll
    for (int h4 = 0; h4 < 8; ++h4) {
      float4 o4 = orow[h4];
      float4 w4 = wrow[h4];
      zacc += o4.x * w4.x + o4.y * w4.y + o4.z * w4.z + o4.w * w4.w;
    }
    float z = y1g[t * 32 + c] + zacc;
    {
      float s1 = gsum32(z), s2 = gsum32(z * z);
      float mu = s1 * (1.0f / 32.0f);
      z = (z - mu) * (1.0f / sqrtf(s2 * (1.0f / 32.0f) - mu * mu + 1e-5f)) * dec_ln2v[c];
    }
    {
      float d1 = gsum32(z * dec_lin1[c]);
      z += fmaxf(d1, 0.f) * dec_lin2[c];
    }
    {
      float s1 = gsum32(z), s2 = gsum32(z * z);
      float mu = s1 * (1.0f / 32.0f);
      z = (z - mu) * (1.0f / sqrtf(s2 * (1.0f / 32.0f) - mu * mu + 1e-5f)) * dec_ln3v[c];
    }
    ls[ZB + t * 32 + c] = z;
  }
  wsync();

  // P7b
  for (int idx = l32; idx < 80; idx += 32) {
    int t = idx >> 3, m = idx & 7;
    const float4* arow = (const float4*)(W_d0 + m * 32);
    const float4* zrow4 = (const float4*)(ls + ZB + t * 32);
    float d = 0.f;
#pragma unroll
    for (int q4 = 0; q4 < 8; ++q4) {
      float4 a4 = arow[q4];
      float4 z4 = zrow4[q4];
      d += a4.x * z4.x + a4.y * z4.y + a4.z * z4.z + a4.w * z4.w;
    }
    ls[OC + idx] = fmaxf(d, 0.f);
  }
  wsync();

  // P7c
  if (l32 < 10) {
    float r = 0.f;
#pragma unroll
    for (int m = 0; m < 8; ++m) r += ls[OC + l32 * 8 + m] * W_d1[m];
    out[((n * 10 + l32) * 30 + pi) * 30 + pj] = r;
  }
}

// ---------------------------------------------------------------------------
extern "C" void kernel_launch(void* const* d_in, const int* in_sizes, int n_in,
                              void* d_out, int out_size, void* d_ws, size_t ws_size,
                              hipStream_t stream) {
  (void)in_sizes; (void)n_in; (void)out_size; (void)ws_size;
  const float* x          = (const float*)d_in[0];
  const float* Vf         = (const float*)d_in[1];
  const float* enc_in     = (const float*)d_in[2];
  const float* enc_outw   = (const float*)d_in[3];
  const float* enc_lin1   = (const float*)d_in[4];
  const float* enc_lin2   = (const float*)d_in[5];
  const float* enc_ln1    = (const float*)d_in[6];
  const float* enc_ln2    = (const float*)d_in[7];
  const float* ffV_w      = (const float*)d_in[8];
  const float* dec_sa_in  = (const float*)d_in[9];
  const float* dec_sa_out = (const float*)d_in[10];
  const float* dec_ca_in  = (const float*)d_in[11];
  const float* dec_ca_out = (const float*)d_in[12];
  const float* dec_lin1   = (const float*)d_in[13];
  const float* dec_lin2   = (const float*)d_in[14];
  const float* dec_ln1    = (const float*)d_in[15];
  const float* dec_ln2    = (const float*)d_in[16];
  const float* dec_ln3    = (const float*)d_in[17];
  const float* W_d0       = (const float*)d_in[18];
  const float* W_d1       = (const float*)d_in[19];
  float* out = (float*)d_out;

  float* ws    = (float*)d_ws;
  float* M_enc = ws;            // 128
  float* WVO   = ws + 128;      // 128
  float* G_k   = ws + 256;      // 320
  float* G_v   = ws + 576;      // 320
  float* y1    = ws + 896;      // 320
  float* qca   = ws + 1216;     // 320  (total 1536 floats)

  hipLaunchKernelGGL(precompute_kernel, dim3(2), dim3(256), 0, stream,
                     Vf, enc_in, enc_outw, ffV_w, dec_sa_in, dec_sa_out,
                     dec_ln1, dec_ca_in, M_enc, WVO, G_k, G_v, y1, qca);

  hipLaunchKernelGGL(pixel_main_v7, dim3(1800), dim3(256), 0, stream,
                     x, M_enc, WVO, enc_lin1, enc_lin2, enc_ln1, enc_ln2,
                     G_k, G_v, y1, qca, dec_ca_out, dec_lin1, dec_lin2,
                     dec_ln2, dec_ln3, W_d0, W_d1, out);

  hipLaunchKernelGGL(pixel_main_v2p, dim3(900), dim3(256), 0, stream,
                     x, M_enc, WVO, enc_lin1, enc_lin2, enc_ln1, enc_ln2,
                     G_k, G_v, y1, qca, dec_ca_out, dec_lin1, dec_lin2,
                     dec_ln2, dec_ln3, W_d0, W_d1, out);
}